// Round 1
// 415.525 us; speedup vs baseline: 1.0128x; 1.0128x over previous
//
#include <hip/hip_runtime.h>

// ---------------- constants ----------------
#define NROWS 16384
#define NF 39
#define NV 100000
#define NE 16
#define HID 400
#define K1 624     // real K of layer 1 (39*16)
#define K1T 640    // padded K span for layer 1 (h0 now zero-padded to this)
#define K2T 448    // padded K span for layers 2/3 (real 400)
#define BN_EPS 1e-5f

typedef short short8v __attribute__((ext_vector_type(8)));
typedef float float4v __attribute__((ext_vector_type(4)));

__device__ __forceinline__ float bf2f(unsigned short u) {
    unsigned int x = ((unsigned int)u) << 16;
    return __uint_as_float(x);
}
__device__ __forceinline__ unsigned short f2bf(float f) {
    unsigned int x = __float_as_uint(f);
    unsigned int r = (x + 0x7FFFu + ((x >> 16) & 1u)) >> 16;
    return (unsigned short)r;
}

// async global->LDS DMA, 16B per lane. LDS dest is wave-uniform base + lane*16.
__device__ __forceinline__ void gload16(const unsigned short* g, unsigned short* l) {
    __builtin_amdgcn_global_load_lds(
        (const __attribute__((address_space(1))) unsigned int*)g,
        (__attribute__((address_space(3))) unsigned int*)l,
        16, 0, 0);
}

// ---------------- prep: embed (blocks 0..4095) + weight-convert + zero sums -------------
#define EMB_BLOCKS 4096
#define W1E (448 * 640)           // 286720
#define W2E (448 * 448)           // 200704
#define TCVT (W1E + 2 * W2E)      // 688128 elems
#define CVT_BLOCKS (TCVT / 8 / 256)   // 336

__global__ __launch_bounds__(256) void prep_kernel(const int* __restrict__ Xi,
                                                   const float* __restrict__ Xv,
                                                   const float* __restrict__ emb1,
                                                   const float* __restrict__ emb2,
                                                   const float* __restrict__ W1,
                                                   const float* __restrict__ W2,
                                                   const float* __restrict__ W3,
                                                   unsigned short* __restrict__ h0,
                                                   float* __restrict__ f12,
                                                   unsigned short* __restrict__ w1b,
                                                   unsigned short* __restrict__ w2b,
                                                   unsigned short* __restrict__ w3b,
                                                   float* __restrict__ sums) {
    int b = blockIdx.x;
    int tid = threadIdx.x;
    if (b < EMB_BLOCKS) {
        int wave = tid >> 6, lane = tid & 63;
        int n = b * 4 + wave;
        __shared__ int sidx[4][NF + 1];
        __shared__ float sxv[4][NF + 1];
        __shared__ __align__(16) float sx[4][NF * NE];
        __shared__ float srn[4][NE];
        if (lane < NF) {
            sidx[wave][lane] = Xi[n * NF + lane];
            sxv[wave][lane] = Xv[n * NF + lane];
        }
        __syncthreads();
        const float4* e2 = (const float4*)emb2;
        for (int i = lane; i < NF * 4; i += 64) {
            int f = i >> 2, q = i & 3;
            float4 v = e2[((size_t)f * NV + (size_t)sidx[wave][f]) * 4 + q];
            float m = sxv[wave][f];
            float4 o; o.x = v.x * m; o.y = v.y * m; o.z = v.z * m; o.w = v.w * m;
            *(float4*)&sx[wave][f * NE + q * 4] = o;
        }
        __syncthreads();
        float f2 = 0.f;
        if (lane < NE) {
            float ss = 0.f, sm = 0.f;
            #pragma unroll
            for (int f = 0; f < NF; ++f) {
                float v = sx[wave][f * NE + lane];
                ss += v * v;
                sm += v;
            }
            float rn = 1.f / fmaxf(sqrtf(ss), 1e-12f);
            srn[wave][lane] = rn;
            float s = sm * rn;
            f2 = 0.5f * (s * s - ss * rn * rn);
        }
        float f1 = 0.f;
        if (lane < NF) {
            f1 = emb1[(size_t)lane * NV + (size_t)sidx[wave][lane]] * sxv[wave][lane];
        }
        float tot = f1 + f2;
        #pragma unroll
        for (int o = 32; o; o >>= 1) tot += __shfl_down(tot, o, 64);
        if (lane == 0) f12[n] = tot;
        __syncthreads();
        // h0 store: now 80 vec8 chunks per row (zero-padded to K1T=640 so gemm1
        // can stage A with global_load_lds without per-chunk masking).
        for (int i = lane; i < 80; i += 64) {
            int k0 = i * 8;
            short8v o = (short8v){0, 0, 0, 0, 0, 0, 0, 0};
            if (i < 78) {
                #pragma unroll
                for (int e = 0; e < 8; ++e) {
                    int k = k0 + e;
                    o[e] = (short)f2bf(sx[wave][k] * srn[wave][k & 15]);
                }
            }
            *(short8v*)(h0 + (size_t)n * K1T + k0) = o;
        }
        return;
    }
    b -= EMB_BLOCKS;
    if (b < CVT_BLOCKS) {
        int gidx = b * 256 + tid;
        int e = gidx * 8;
        if (e < TCVT) {
            const float* W; unsigned short* O; int Kreal, Kt, base;
            if (e < W1E) { W = W1; O = w1b; Kreal = K1; Kt = K1T; base = 0; }
            else if (e < W1E + W2E) { W = W2; O = w2b; Kreal = HID; Kt = K2T; base = W1E; }
            else { W = W3; O = w3b; Kreal = HID; Kt = K2T; base = W1E + W2E; }
            int le = e - base;
            int r = le / Kt, k = le % Kt;
            short8v o;
            #pragma unroll
            for (int ee = 0; ee < 8; ++ee) {
                int kk = k + ee;
                o[ee] = (r < HID && kk < Kreal) ? (short)f2bf(W[(size_t)r * Kreal + kk]) : (short)0;
            }
            *(short8v*)(O + (size_t)r * Kt + k) = o;
        }
        return;
    }
    for (int i = tid; i < 2400; i += 256) sums[i] = 0.f;
}

// ---------------- bf16 MFMA GEMM: 512 thr, BM=128, BNT=224 ----------------------------
// v2: double-buffered LDS, ONE barrier per K-step (was two), B (and A for layer 1)
// staged via global_load_lds width=16. LDS row stride = 64 elems (128B, no pad);
// bank spread restored via XOR chunk swizzle: LDS[r][c] holds global chunk c^(r&7),
// applied on BOTH the stage source address and the fragment read (rule: both-sides).
#define BM 128
#define BNT 224
#define BK 64

template <bool FUSE_BN>
__global__ __launch_bounds__(512, 2) void gemm_kernel(const unsigned short* __restrict__ A,
                                                      int lda, int Kreal, int Kt,
                                                      const unsigned short* __restrict__ W,  // 448 x Kt
                                                      const float* __restrict__ bias,
                                                      const float* __restrict__ psums,
                                                      const float* __restrict__ g,
                                                      const float* __restrict__ bt,
                                                      unsigned short* __restrict__ C,        // ldc = 400
                                                      float* __restrict__ sums) {
    __shared__ __align__(16) unsigned short As[2][BM * BK];    // 2 x 16 KB
    __shared__ __align__(16) unsigned short Bs[2][BNT * BK];   // 2 x 28 KB
    __shared__ float ssc[K2T], ssh[K2T];
    __shared__ float scol[BNT], qcol[BNT];
    int tid = threadIdx.x;
    int wave = tid >> 6, lane = tid & 63;
    int quad = lane >> 4, l16 = lane & 15;
    int mi = wave & 3, nj = wave >> 2;
    int m0 = blockIdx.x * BM;
    int n0 = blockIdx.y * BNT;
    int wbase = tid & ~63;   // wave*64

    if (FUSE_BN && tid < K2T) {
        float sc = 0.f, sh = 0.f;
        if (tid < HID) {
            const float invN = 1.f / (float)NROWS;
            float mu = psums[tid] * invN;
            float var = psums[HID + tid] * invN - mu * mu;
            float rstd = rsqrtf(var + BN_EPS);
            sc = g[tid] * rstd;
            sh = bt[tid] - mu * sc;
        }
        ssc[tid] = sc; ssh[tid] = sh;
    }
    if (tid < BNT) { scol[tid] = 0.f; qcol[tid] = 0.f; }

    const short8v zero8 = (short8v){0, 0, 0, 0, 0, 0, 0, 0};
    short8v Ar[2];

    // layer-1 A staging: async DMA, inverse-swizzled global source
    auto stageA_g = [&](int buf, int kt) {
        #pragma unroll
        for (int i = 0; i < 2; ++i) {
            int v = tid + i * 512;
            int r = v >> 3, c = v & 7;
            int sc = c ^ (r & 7);
            gload16(A + (size_t)(m0 + r) * lda + kt + sc * 8,
                    &As[buf][(size_t)(i * 512 + wbase) * 8]);
        }
    };
    // B staging: async DMA (224 rows = 3.5 issues; issue 3 is waves 0..3 only — wave-uniform)
    auto stageB = [&](int buf, int kt) {
        #pragma unroll
        for (int i = 0; i < 4; ++i) {
            int v = tid + i * 512;
            if (v < BNT * 8) {
                int r = v >> 3, c = v & 7;
                int sc = c ^ (r & 7);
                gload16(W + (size_t)(n0 + r) * Kt + kt + sc * 8,
                        &Bs[buf][(size_t)(i * 512 + wbase) * 8]);
            }
        }
    };
    // layers 2/3 A staging: reg load (natural chunk order, coalesced), BN+ReLU, swizzled ds_write
    auto loadA_regs = [&](int kt) {
        #pragma unroll
        for (int i = 0; i < 2; ++i) {
            int v = tid + i * 512;
            int r = v >> 3, gc = v & 7;
            int k = kt + gc * 8;
            Ar[i] = (k < Kreal) ? *(const short8v*)(A + (size_t)(m0 + r) * lda + k) : zero8;
        }
    };
    auto writeA_lds = [&](int buf, int kt) {
        #pragma unroll
        for (int i = 0; i < 2; ++i) {
            int v = tid + i * 512;
            int r = v >> 3, gc = v & 7;
            short8v val = Ar[i];
            #pragma unroll
            for (int e = 0; e < 8; ++e) {
                int k = kt + gc * 8 + e;
                float x = bf2f((unsigned short)val[e]);
                val[e] = (short)f2bf(fmaxf(x * ssc[k] + ssh[k], 0.f));
            }
            *(short8v*)(&As[buf][r * BK + ((gc ^ (r & 7)) * 8)]) = val;
        }
    };

    float4v acc[2][7];
    #pragma unroll
    for (int i = 0; i < 2; ++i)
        #pragma unroll
        for (int f = 0; f < 7; ++f)
            acc[i][f] = (float4v){0.f, 0.f, 0.f, 0.f};

    // prologue: stage tile 0
    if (FUSE_BN) loadA_regs(0); else stageA_g(0, 0);
    stageB(0, 0);
    __syncthreads();                       // ssc/ssh ready; DMA tile 0 drained
    if (FUSE_BN) { writeA_lds(0, 0); __syncthreads(); }

    int buf = 0;
    for (int kt = 0; kt < Kt; kt += BK) {
        int nxt = kt + BK;
        bool more = nxt < Kt;
        if (more) {
            if (FUSE_BN) loadA_regs(nxt); else stageA_g(buf ^ 1, nxt);
            stageB(buf ^ 1, nxt);          // async: in flight across the MFMA phase
        }
        __builtin_amdgcn_s_setprio(1);
        #pragma unroll
        for (int kk = 0; kk < BK; kk += 32) {
            int kc = kk >> 3;              // 0 or 4
            short8v af[2], bfr[7];
            #pragma unroll
            for (int i = 0; i < 2; ++i) {
                int r = mi * 32 + i * 16 + l16;
                af[i] = *(const short8v*)(&As[buf][r * BK + (((quad + kc) ^ (r & 7)) * 8)]);
            }
            #pragma unroll
            for (int f = 0; f < 7; ++f) {
                int r = nj * 112 + f * 16 + l16;
                bfr[f] = *(const short8v*)(&Bs[buf][r * BK + (((quad + kc) ^ (r & 7)) * 8)]);
            }
            #pragma unroll
            for (int i = 0; i < 2; ++i)
                #pragma unroll
                for (int f = 0; f < 7; ++f)
                    acc[i][f] = __builtin_amdgcn_mfma_f32_16x16x32_bf16(af[i], bfr[f], acc[i][f], 0, 0, 0);
        }
        __builtin_amdgcn_s_setprio(0);
        if (FUSE_BN && more) writeA_lds(buf ^ 1, nxt);  // flat A loads hid under MFMA
        __syncthreads();                   // single barrier: drains DMA + ds_writes
        buf ^= 1;
    }

    // epilogue: store C + per-column stats. C/D layout: col=lane&15, row=quad*4+reg
    #pragma unroll
    for (int f = 0; f < 7; ++f) {
        int lc = nj * 112 + f * 16 + l16;
        int col = n0 + lc;
        float bv = (col < HID) ? bias[col] : 0.f;
        float s = 0.f, q = 0.f;
        #pragma unroll
        for (int i = 0; i < 2; ++i) {
            #pragma unroll
            for (int r = 0; r < 4; ++r) {
                int row = m0 + mi * 32 + i * 16 + quad * 4 + r;
                float v = acc[i][f][r] + bv;
                if (col < HID) C[(size_t)row * HID + col] = f2bf(v);
                s += v;
                q += v * v;
            }
        }
        s += __shfl_down(s, 32, 64); s += __shfl_down(s, 16, 64);
        q += __shfl_down(q, 32, 64); q += __shfl_down(q, 16, 64);
        if (lane < 16) {
            atomicAdd(&scol[lc], s);
            atomicAdd(&qcol[lc], q);
        }
    }
    __syncthreads();
    if (tid < BNT) {
        int col = n0 + tid;
        if (col < HID) {
            atomicAdd(&sums[col], scol[tid]);
            atomicAdd(&sums[HID + col], qcol[tid]);
        }
    }
}

// ---------------- final: finalize3 (in-block, strided fill) + BN3+ReLU+rowsum --------------
__global__ __launch_bounds__(256) void final_kernel(const unsigned short* __restrict__ H3,
                                                    const float* __restrict__ sums,
                                                    const float* __restrict__ g,
                                                    const float* __restrict__ bt,
                                                    const float* __restrict__ f12,
                                                    const float* __restrict__ bias,
                                                    float* __restrict__ out) {
    __shared__ float ssc[HID], ssh[HID];
    int tid = threadIdx.x;
    const float invN = 1.f / (float)NROWS;
    for (int j = tid; j < HID; j += 256) {   // strided: 256 threads cover 400 columns
        float mu = sums[j] * invN;
        float var = sums[HID + j] * invN - mu * mu;
        float rstd = rsqrtf(var + BN_EPS);
        float sc = g[j] * rstd;
        ssc[j] = sc;
        ssh[j] = bt[j] - mu * sc;
    }
    __syncthreads();
    int wave = tid >> 6, lane = tid & 63;
    int n = blockIdx.x * 4 + wave;
    float acc = 0.f;
    if (lane < 50) {
        short8v v = *(const short8v*)(H3 + (size_t)n * HID + lane * 8);
        #pragma unroll
        for (int e = 0; e < 8; ++e) {
            int k = lane * 8 + e;
            float x = bf2f((unsigned short)v[e]) * ssc[k] + ssh[k];
            acc += fmaxf(x, 0.f);
        }
    }
    #pragma unroll
    for (int o = 32; o; o >>= 1) acc += __shfl_down(acc, o, 64);
    if (lane == 0) out[n] = acc + f12[n] + bias[0];
}

// ---------------- launch ----------------
extern "C" void kernel_launch(void* const* d_in, const int* in_sizes, int n_in,
                              void* d_out, int out_size, void* d_ws, size_t ws_size,
                              hipStream_t stream) {
    const int* Xi = (const int*)d_in[0];
    const float* Xv = (const float*)d_in[1];
    const float* emb1 = (const float*)d_in[2];
    const float* emb2 = (const float*)d_in[3];
    const float* W1 = (const float*)d_in[4];
    const float* b1 = (const float*)d_in[5];
    const float* g1 = (const float*)d_in[6];
    const float* bt1 = (const float*)d_in[7];
    const float* W2 = (const float*)d_in[8];
    const float* b2 = (const float*)d_in[9];
    const float* g2 = (const float*)d_in[10];
    const float* bt2 = (const float*)d_in[11];
    const float* W3 = (const float*)d_in[12];
    const float* b3 = (const float*)d_in[13];
    const float* g3 = (const float*)d_in[14];
    const float* bt3 = (const float*)d_in[15];
    const float* bias = (const float*)d_in[16];

    char* ws = (char*)d_ws;
    size_t o_f12 = 0;
    size_t o_h0  = 65536;
    size_t o_h1  = o_h0 + (size_t)NROWS * K1T * 2;   // h0 now 16384 x 640 bf16
    size_t o_w1  = o_h1 + (size_t)NROWS * HID * 2;
    size_t o_w2  = o_w1 + (size_t)448 * K1T * 2;
    size_t o_w3  = o_w2 + (size_t)448 * K2T * 2;
    size_t o_sums = o_w3 + (size_t)448 * K2T * 2;

    float* f12 = (float*)(ws + o_f12);
    unsigned short* h0 = (unsigned short*)(ws + o_h0);
    unsigned short* h1 = (unsigned short*)(ws + o_h1);
    unsigned short* h2 = (unsigned short*)(ws + o_h0);   // alias: h0 dead after gemm1
    unsigned short* h3 = (unsigned short*)(ws + o_h1);   // alias: h1 dead after gemm2
    unsigned short* w1b = (unsigned short*)(ws + o_w1);
    unsigned short* w2b = (unsigned short*)(ws + o_w2);
    unsigned short* w3b = (unsigned short*)(ws + o_w3);
    float* sums1 = (float*)(ws + o_sums);
    float* sums2 = sums1 + 800;
    float* sums3 = sums2 + 800;
    float* out = (float*)d_out;

    prep_kernel<<<EMB_BLOCKS + CVT_BLOCKS + 1, 256, 0, stream>>>(
        Xi, Xv, emb1, emb2, W1, W2, W3, h0, f12, w1b, w2b, w3b, sums1);

    dim3 ggrid(NROWS / BM, 2);

    gemm_kernel<false><<<ggrid, 512, 0, stream>>>(h0, K1T, K1T, K1T, w1b, b1,
                                                  nullptr, nullptr, nullptr, h1, sums1);
    gemm_kernel<true><<<ggrid, 512, 0, stream>>>(h1, HID, HID, K2T, w2b, b2,
                                                 sums1, g1, bt1, h2, sums2);
    gemm_kernel<true><<<ggrid, 512, 0, stream>>>(h2, HID, HID, K2T, w3b, b3,
                                                 sums2, g2, bt2, h3, sums3);
    final_kernel<<<NROWS / 4, 256, 0, stream>>>(h3, sums3, g3, bt3, f12, bias, out);
}